// Round 6
// baseline (603.198 us; speedup 1.0000x reference)
//
#include <hip/hip_runtime.h>
#include <hip/hip_cooperative_groups.h>

namespace cg = cooperative_groups;

#define NN 100000
#define NE 600000
#define ET (NE + NN)
#define D 128
#define NREL 16
#define SCANB 391   // 391*256 = 100096 >= NN
#define TPB 4
#define MAXTILES 10954
#define GEMMG ((MAXTILES + TPB - 1) / TPB)
#define WGRID 1088  // 17*16384/256
#define WTN (17 * 16384)
#define XCN (NN * D / 4)

typedef short short8 __attribute__((ext_vector_type(8)));
typedef float f32x4 __attribute__((ext_vector_type(4)));
typedef unsigned int u32x4 __attribute__((ext_vector_type(4)));

// meta layout (ints)
#define C0 0    // counts[17]
#define O0 20   // offsets[18]
#define CU0 40  // cursors[17]
#define T0 60   // tileoff[18]

// ws layout (bytes)
#define WT_OFF   0
#define META_OFF 557056
#define DH_OFF   557568
#define DO_OFF   957568
#define DC_OFF   1357576
#define BS_OFF   1757576
#define SCP_OFF  1759576
#define SR_OFF   7360088
#define XB_OFF   10160096
#define MSGB_OFF 35760096
#define MSGA_OFF 10160096
#define NEED_B   (MSGB_OFF + (size_t)ET * 128 * 2)
#define NEED_A   (MSGA_OFF + (size_t)ET * 128 * 2)

__device__ __forceinline__ unsigned short f2bf(float f) {
  unsigned u = __builtin_bit_cast(unsigned, f);
  u += 0x7fffu + ((u >> 16) & 1u);   // RNE; inputs finite/normal
  return (unsigned short)(u >> 16);
}

// ======================= fused cooperative kernel =======================
struct GemmSm {
  short As[64 * 17 * 8];
  short Es[64 * 136];
  int Pos2[2][64];
  int Ms[80];
};
union Sm {
  GemmSm g;
  int sh[256];
  int s2[SCANB];
  struct { int h[16]; int base[16]; int lh[16]; } sc;
  int hist[16];
};

__global__ __launch_bounds__(256) void k_fused(const float* __restrict__ x,
    const int* __restrict__ ei, const int* __restrict__ et,
    const float* __restrict__ bases, const float* __restrict__ coef,
    const float* __restrict__ w_self, unsigned short* __restrict__ wT,
    int* __restrict__ meta, int* __restrict__ dstHist, int* __restrict__ dstOff,
    int* __restrict__ dstCursor, int* __restrict__ blockSums,
    int2* __restrict__ sCP, unsigned short* __restrict__ xb,
    unsigned short* __restrict__ msg, float* __restrict__ out)
{
  cg::grid_group gg = cg::this_grid();
  __shared__ Sm sm;
  int tid = threadIdx.x;
  int gstride = gridDim.x * 256;
  int gt = blockIdx.x * 256 + tid;

  // ---- phase 0: zero meta + dstHist ----
  for (int i = gt; i < NN + 128; i += gstride) {
    if (i < 128) meta[i] = 0; else dstHist[i - 128] = 0;
  }
  gg.sync();

  // ---- phase 1a: wT + xcast (flat element work) ----
  for (int u = gt; u < WTN + XCN; u += gstride) {
    if (u < WTN) {
      int r = u >> 14, t = u & 16383;
      float v;
      if (r < 16) {
        int o = t >> 7, i = t & 127;
        float acc = 0.f;
        #pragma unroll
        for (int b = 0; b < 8; ++b)
          acc += coef[r * 8 + b] * bases[b * 16384 + i * 128 + o];
        v = acc;
      } else {
        v = w_self[t];
      }
      wT[u] = f2bf(v);
    } else {
      int i = u - WTN;
      float4 f = *(const float4*)(x + (size_t)i * 4);
      unsigned short s0 = f2bf(f.x), s1 = f2bf(f.y), s2v = f2bf(f.z), s3 = f2bf(f.w);
      unsigned long long pk = (unsigned long long)s0 | ((unsigned long long)s1 << 16)
                            | ((unsigned long long)s2v << 32) | ((unsigned long long)s3 << 48);
      *(unsigned long long*)(xb + (size_t)i * 4) = pk;
    }
  }
  // ---- phase 1b: histograms (rel in LDS, dst global) ----
  __syncthreads();
  if (tid < 16) sm.hist[tid] = 0;
  __syncthreads();
  for (int e = gt; e < NE; e += gstride) {
    atomicAdd(&sm.hist[et[e]], 1);
    atomicAdd(&dstHist[ei[e]], 1);
  }
  __syncthreads();
  if (tid < 16) atomicAdd(&meta[C0 + tid], sm.hist[tid]);
  gg.sync();

  // ---- phase 2a: per-256 local exclusive scan of (dstHist+1) ----
  for (int v = blockIdx.x; v < SCANB; v += gridDim.x) {
    int d = v * 256 + tid;
    int val = (d < NN) ? (dstHist[d] + 1) : 0;
    sm.sh[tid] = val;
    __syncthreads();
    #pragma unroll
    for (int ofs = 1; ofs < 256; ofs <<= 1) {
      int t = (tid >= ofs) ? sm.sh[tid - ofs] : 0;
      __syncthreads();
      sm.sh[tid] += t;
      __syncthreads();
    }
    if (d < NN) dstOff[d] = sm.sh[tid] - val;
    if (tid == 255) blockSums[v] = sm.sh[tid];
    __syncthreads();
  }
  gg.sync();

  // ---- phase 2b: scan block sums + rel prefix (block 0) ----
  if (blockIdx.x == 0) {
    for (int i = tid; i < SCANB; i += 256) sm.s2[i] = blockSums[i];
    __syncthreads();
    if (tid == 0) {
      int run = 0;
      for (int i = 0; i < SCANB; ++i) { int c = sm.s2[i]; sm.s2[i] = run; run += c; }
      meta[C0 + 16] = NN;
      int off = 0, toff = 0;
      for (int r = 0; r <= 16; ++r) {
        meta[O0 + r] = off;
        meta[CU0 + r] = off;
        meta[T0 + r] = toff;
        int c = meta[C0 + r];
        off += c;
        toff += (c + 63) >> 6;
      }
      meta[O0 + 17] = off;
      meta[T0 + 17] = toff;
    }
    __syncthreads();
    for (int i = tid; i < SCANB; i += 256) blockSums[i] = sm.s2[i];
  }
  gg.sync();

  // ---- phase 2c: finalize dstOff, cursors, self edges ----
  for (int v = blockIdx.x; v < SCANB; v += gridDim.x) {
    int d = v * 256 + tid;
    int base = blockSums[v];
    if (d < NN) {
      int o = dstOff[d] + base;
      dstOff[d] = o;
      dstCursor[d] = o + 1;
      sCP[NE + d] = make_int2(d, o);
    }
    if (d == NN) dstOff[NN] = ET;
  }
  gg.sync();

  // ---- phase 3: scatter edges into rel buckets with dst-sorted slots ----
  for (int v = blockIdx.x; v * 4096 < NE; v += gridDim.x) {
    int start = v * 4096;
    int end = min(NE, start + 4096);
    if (tid < 16) { sm.sc.h[tid] = 0; sm.sc.lh[tid] = 0; }
    __syncthreads();
    for (int e = start + tid; e < end; e += 256)
      atomicAdd(&sm.sc.h[et[e]], 1);
    __syncthreads();
    if (tid < 16) sm.sc.base[tid] = atomicAdd(&meta[CU0 + tid], sm.sc.h[tid]);
    __syncthreads();
    for (int e = start + tid; e < end; e += 256) {
      int r = et[e];
      int row = ei[e];
      int pos = sm.sc.base[r] + atomicAdd(&sm.sc.lh[r], 1);
      int slot = atomicAdd(&dstCursor[row], 1);
      sCP[pos] = make_int2(ei[NE + e], slot);
    }
    __syncthreads();
  }
  gg.sync();

  // ---- phase 4: grouped MFMA GEMM, contiguous tile range per block ----
  if (tid < 80) sm.g.Ms[tid] = meta[tid];
  __syncthreads();
  {
    int ntiles = sm.g.Ms[T0 + 17];
    int chunk = (ntiles + gridDim.x - 1) / gridDim.x;
    int t0 = blockIdx.x * chunk;
    int t1 = min(ntiles, t0 + chunk);
    int lane = tid & 63, wave = tid >> 6;
    int q = lane >> 4, l15 = lane & 15;
    int m = tid >> 2, ug = tid & 3;

    if (t0 < t1) {
      short8 pf[4];
      int pcy = 0;
      bool pvalid = false;
      int r = 0, nr = 0;
      {
        while (r < 16 && sm.g.Ms[T0 + r + 1] <= t0) ++r;
        int boff = sm.g.Ms[O0 + r];
        int e0 = boff + (t0 - sm.g.Ms[T0 + r]) * 64;
        nr = min(64, boff + sm.g.Ms[C0 + r] - e0);
        pvalid = m < nr;
        int2 cp = sCP[pvalid ? (e0 + m) : e0];
        pcy = cp.y;
        const unsigned short* xr = xb + (size_t)cp.x * 128;
        #pragma unroll
        for (int s = 0; s < 4; ++s) {
          short8 v = (short8)(short)0;
          if (pvalid) v = *(const short8*)(xr + (ug * 4 + s) * 8);
          pf[s] = v;
        }
      }
      int rprev = -1;
      short8 bfr[2][4];
      for (int b = t0; b < t1; ++b) {
        int curR = r, curNr = nr;
        #pragma unroll
        for (int s = 0; s < 4; ++s)
          *(short8*)&sm.g.As[(m * 17 + ug * 4 + s) * 8] = pf[s];
        if (ug == 0) sm.g.Pos2[b & 1][m] = pvalid ? pcy : 0;
        __syncthreads();   // sync1
        int bn = b + 1;
        if (bn < t1) {
          int rn = curR;
          while (rn < 16 && sm.g.Ms[T0 + rn + 1] <= bn) ++rn;
          int boff = sm.g.Ms[O0 + rn];
          int e0n = boff + (bn - sm.g.Ms[T0 + rn]) * 64;
          int nrn = min(64, boff + sm.g.Ms[C0 + rn] - e0n);
          pvalid = m < nrn;
          int2 cp = sCP[pvalid ? (e0n + m) : e0n];
          pcy = cp.y;
          const unsigned short* xr = xb + (size_t)cp.x * 128;
          #pragma unroll
          for (int s = 0; s < 4; ++s) {
            short8 v = (short8)(short)0;
            if (pvalid) v = *(const short8*)(xr + (ug * 4 + s) * 8);
            pf[s] = v;
          }
          r = rn; nr = nrn;
        }
        if (curR != rprev) {
          const unsigned short* wr = wT + curR * 16384;
          #pragma unroll
          for (int ns = 0; ns < 2; ++ns)
            #pragma unroll
            for (int kk = 0; kk < 4; ++kk)
              bfr[ns][kk] = *(const short8*)(wr + (wave * 32 + ns * 16 + l15) * 128 + kk * 32 + q * 8);
          rprev = curR;
        }
        f32x4 acc[4][2];
        #pragma unroll
        for (int ms = 0; ms < 4; ++ms)
          #pragma unroll
          for (int ns = 0; ns < 2; ++ns)
            acc[ms][ns] = (f32x4){0.f, 0.f, 0.f, 0.f};
        #pragma unroll
        for (int kk = 0; kk < 4; ++kk) {
          short8 af[4];
          #pragma unroll
          for (int ms = 0; ms < 4; ++ms)
            af[ms] = *(const short8*)&sm.g.As[((ms * 16 + l15) * 17 + kk * 4 + q) * 8];
          #pragma unroll
          for (int ms = 0; ms < 4; ++ms)
            #pragma unroll
            for (int ns = 0; ns < 2; ++ns)
              acc[ms][ns] = __builtin_amdgcn_mfma_f32_16x16x32_bf16(af[ms], bfr[ns][kk], acc[ms][ns], 0, 0, 0);
        }
        #pragma unroll
        for (int ms = 0; ms < 4; ++ms)
          #pragma unroll
          for (int ns = 0; ns < 2; ++ns)
            #pragma unroll
            for (int reg = 0; reg < 4; ++reg)
              sm.g.Es[(ms * 16 + q * 4 + reg) * 136 + wave * 32 + ns * 16 + l15] =
                  (short)f2bf(acc[ms][ns][reg]);
        __syncthreads();   // sync2
        #pragma unroll
        for (int i = 0; i < 4; ++i) {
          int row = wave * 16 + i * 4 + q;
          short8 v = *(const short8*)&sm.g.Es[row * 136 + l15 * 8];
          if (row < curNr)
            *(short8*)(msg + (size_t)sm.g.Pos2[b & 1][row] * 128 + l15 * 8) = v;
        }
      }
    }
  }
  gg.sync();

  // ---- phase 5: segment reduce, 16-lane group per dst ----
  for (int d = blockIdx.x * 16 + (tid >> 4); d < NN; d += gridDim.x * 16) {
    int sl = tid & 15;
    int s = dstOff[d], e = dstOff[d + 1];
    const unsigned short* base = msg + (size_t)sl * 8;
    float a[8], bacc[8];
    #pragma unroll
    for (int i = 0; i < 8; ++i) { a[i] = 0.f; bacc[i] = 0.f; }
    int j = s;
    for (; j + 1 < e; j += 2) {
      u32x4 v0 = *(const u32x4*)(base + (size_t)j * 128);
      u32x4 v1 = *(const u32x4*)(base + (size_t)(j + 1) * 128);
      #pragma unroll
      for (int c = 0; c < 4; ++c) {
        a[2 * c]     += __builtin_bit_cast(float, v0[c] << 16);
        a[2 * c + 1] += __builtin_bit_cast(float, v0[c] & 0xffff0000u);
        bacc[2 * c]     += __builtin_bit_cast(float, v1[c] << 16);
        bacc[2 * c + 1] += __builtin_bit_cast(float, v1[c] & 0xffff0000u);
      }
    }
    if (j < e) {
      u32x4 v0 = *(const u32x4*)(base + (size_t)j * 128);
      #pragma unroll
      for (int c = 0; c < 4; ++c) {
        a[2 * c]     += __builtin_bit_cast(float, v0[c] << 16);
        a[2 * c + 1] += __builtin_bit_cast(float, v0[c] & 0xffff0000u);
      }
    }
    float4 w0, w1;
    w0.x = a[0] + bacc[0]; w0.y = a[1] + bacc[1]; w0.z = a[2] + bacc[2]; w0.w = a[3] + bacc[3];
    w1.x = a[4] + bacc[4]; w1.y = a[5] + bacc[5]; w1.z = a[6] + bacc[6]; w1.w = a[7] + bacc[7];
    float* op = out + (size_t)d * 128 + sl * 8;
    *(float4*)op = w0;
    *(float4*)(op + 4) = w1;
  }
}

// ======================= R5 fallback kernels =======================
__global__ __launch_bounds__(256) void k_prep(const float* __restrict__ bases,
    const float* __restrict__ coef, const float* __restrict__ w_self,
    unsigned short* __restrict__ wT, const float* __restrict__ x,
    unsigned short* __restrict__ xb)
{
  if (blockIdx.x < WGRID) {
    int idx = blockIdx.x * 256 + threadIdx.x;
    int r = idx >> 14;
    int t = idx & 16383;
    float v;
    if (r < 16) {
      int o = t >> 7, i = t & 127;
      float acc = 0.f;
      #pragma unroll
      for (int b = 0; b < 8; ++b)
        acc += coef[r * 8 + b] * bases[b * 16384 + i * 128 + o];
      v = acc;
    } else {
      v = w_self[t];
    }
    wT[idx] = f2bf(v);
  } else {
    int i = (blockIdx.x - WGRID) * 256 + threadIdx.x;
    if (i >= XCN) return;
    float4 f = *(const float4*)(x + (size_t)i * 4);
    unsigned short s0 = f2bf(f.x), s1 = f2bf(f.y), s2 = f2bf(f.z), s3 = f2bf(f.w);
    unsigned long long pk = (unsigned long long)s0 | ((unsigned long long)s1 << 16)
                          | ((unsigned long long)s2 << 32) | ((unsigned long long)s3 << 48);
    *(unsigned long long*)(xb + (size_t)i * 4) = pk;
  }
}

__global__ __launch_bounds__(256) void k_hist(const int* __restrict__ ei,
    const int* __restrict__ et, int* __restrict__ meta, int* __restrict__ dstHist)
{
  __shared__ int h[16];
  int tid = threadIdx.x;
  if (tid < 16) h[tid] = 0;
  __syncthreads();
  for (int e = blockIdx.x * 256 + tid; e < NE; e += gridDim.x * 256) {
    atomicAdd(&h[et[e]], 1);
    atomicAdd(&dstHist[ei[e]], 1);
  }
  __syncthreads();
  if (tid < 16) atomicAdd(&meta[C0 + tid], h[tid]);
}

__global__ __launch_bounds__(256) void k_scan1(const int* __restrict__ dstHist,
    int* __restrict__ dstOff, int* __restrict__ blockSums)
{
  __shared__ int sh[256];
  int tid = threadIdx.x;
  int d = blockIdx.x * 256 + tid;
  int v = (d < NN) ? (dstHist[d] + 1) : 0;
  sh[tid] = v;
  __syncthreads();
  #pragma unroll
  for (int ofs = 1; ofs < 256; ofs <<= 1) {
    int t = (tid >= ofs) ? sh[tid - ofs] : 0;
    __syncthreads();
    sh[tid] += t;
    __syncthreads();
  }
  if (d < NN) dstOff[d] = sh[tid] - v;
  if (tid == 255) blockSums[blockIdx.x] = sh[tid];
}

__global__ __launch_bounds__(512) void k_scan2(int* __restrict__ blockSums, int* __restrict__ meta)
{
  __shared__ int sh[SCANB];
  int tid = threadIdx.x;
  if (tid < SCANB) sh[tid] = blockSums[tid];
  __syncthreads();
  if (tid == 0) {
    int run = 0;
    for (int i = 0; i < SCANB; ++i) { int c = sh[i]; sh[i] = run; run += c; }
    meta[C0 + 16] = NN;
    int off = 0, toff = 0;
    for (int r = 0; r <= 16; ++r) {
      meta[O0 + r] = off;
      meta[CU0 + r] = off;
      meta[T0 + r] = toff;
      int c = meta[C0 + r];
      off += c;
      toff += (c + 63) >> 6;
    }
    meta[O0 + 17] = off;
    meta[T0 + 17] = toff;
  }
  __syncthreads();
  if (tid < SCANB) blockSums[tid] = sh[tid];
}

__global__ __launch_bounds__(256) void k_scan3(int* __restrict__ dstOff,
    const int* __restrict__ blockSums, int* __restrict__ dstCursor,
    int2* __restrict__ sCP)
{
  int tid = threadIdx.x;
  int d = blockIdx.x * 256 + tid;
  int base = blockSums[blockIdx.x];
  if (d < NN) {
    int o = dstOff[d] + base;
    dstOff[d] = o;
    dstCursor[d] = o + 1;
    sCP[NE + d] = make_int2(d, o);
  }
  if (d == NN) dstOff[NN] = ET;
}

__global__ __launch_bounds__(256) void k_self0(int2* __restrict__ sCP, int* __restrict__ sRow)
{
  int n = blockIdx.x * 256 + threadIdx.x;
  if (n < NN) { sCP[NE + n] = make_int2(n, 0); sRow[NE + n] = n; }
}

__global__ __launch_bounds__(256) void k_scatter(const int* __restrict__ ei, const int* __restrict__ et,
    int* __restrict__ meta, int2* __restrict__ sCP, int* __restrict__ sRow,
    int* __restrict__ dstCursor, int doMsg)
{
  __shared__ int h[16], base[16], lh[16];
  int tid = threadIdx.x;
  int start = blockIdx.x * 4096;
  int end = min(NE, start + 4096);
  if (tid < 16) { h[tid] = 0; lh[tid] = 0; }
  __syncthreads();
  for (int e = start + tid; e < end; e += 256)
    atomicAdd(&h[et[e]], 1);
  __syncthreads();
  if (tid < 16) base[tid] = atomicAdd(&meta[CU0 + tid], h[tid]);
  __syncthreads();
  for (int e = start + tid; e < end; e += 256) {
    int r = et[e];
    int row = ei[e];
    int pos = base[r] + atomicAdd(&lh[r], 1);
    int slot = doMsg ? atomicAdd(&dstCursor[row], 1) : 0;
    sCP[pos] = make_int2(ei[NE + e], slot);
    if (!doMsg) sRow[pos] = row;
  }
}

__global__ __launch_bounds__(256) void k_gemm(const float* __restrict__ xf,
    const unsigned short* __restrict__ xb,
    const unsigned short* __restrict__ wT, const int* __restrict__ meta,
    const int2* __restrict__ sCP, const int* __restrict__ sRow,
    unsigned short* __restrict__ msg, float* __restrict__ out,
    int xbf, int msgmode)
{
  __shared__ short As[64 * 17 * 8];
  __shared__ short Es[64 * 136];
  __shared__ int Pos2[2][64];
  __shared__ int Rows[64];
  __shared__ int Ms[80];

  int tid = threadIdx.x;
  if (tid < 80) Ms[tid] = meta[tid];
  __syncthreads();
  int ntiles = Ms[T0 + 17];

  int lane = tid & 63, wave = tid >> 6;
  int q = lane >> 4, l15 = lane & 15;
  int m = tid >> 2, ug = tid & 3;

  int rprev = -1;
  short8 bfr[2][4];
  for (int ti = 0; ti < TPB; ++ti) {
    int b = blockIdx.x * TPB + ti;
    if (b >= ntiles) break;
    int r = 0;
    while (r < 16 && Ms[T0 + r + 1] <= b) ++r;
    int tile = b - Ms[T0 + r];
    int boff = Ms[O0 + r];
    int e0 = boff + tile * 64;
    int nrows = min(64, boff + Ms[C0 + r] - e0);

    bool valid = m < nrows;
    int e = valid ? (e0 + m) : e0;
    int2 cp = sCP[e];
    if (ug == 0) {
      Pos2[0][m] = valid ? cp.y : 0;
      if (!msgmode) Rows[m] = valid ? sRow[e] : 0;
    }
    int c = cp.x;
    if (xbf) {
      const unsigned short* xr = xb + (size_t)c * 128;
      #pragma unroll
      for (int s = 0; s < 4; ++s) {
        int u = ug * 4 + s;
        short8 pk = (short8)(short)0;
        if (valid) pk = *(const short8*)(xr + u * 8);
        *(short8*)&As[(m * 17 + u) * 8] = pk;
      }
    } else {
      const float* xr = xf + (size_t)c * 128;
      #pragma unroll
      for (int s = 0; s < 4; ++s) {
        int u = ug * 4 + s;
        float4 f0 = make_float4(0.f, 0.f, 0.f, 0.f), f1 = f0;
        if (valid) {
          f0 = *(const float4*)(xr + u * 8);
          f1 = *(const float4*)(xr + u * 8 + 4);
        }
        short8 pk;
        pk[0] = (short)f2bf(f0.x); pk[1] = (short)f2bf(f0.y);
        pk[2] = (short)f2bf(f0.z); pk[3] = (short)f2bf(f0.w);
        pk[4] = (short)f2bf(f1.x); pk[5] = (short)f2bf(f1.y);
        pk[6] = (short)f2bf(f1.z); pk[7] = (short)f2bf(f1.w);
        *(short8*)&As[(m * 17 + u) * 8] = pk;
      }
    }
    __syncthreads();

    if (r != rprev) {
      const unsigned short* wr = wT + r * 16384;
      #pragma unroll
      for (int ns = 0; ns < 2; ++ns)
        #pragma unroll
        for (int kk = 0; kk < 4; ++kk)
          bfr[ns][kk] = *(const short8*)(wr + (wave * 32 + ns * 16 + l15) * 128 + kk * 32 + q * 8);
      rprev = r;
    }

    f32x4 acc[4][2];
    #pragma unroll
    for (int ms = 0; ms < 4; ++ms)
      #pragma unroll
      for (int ns = 0; ns < 2; ++ns)
        acc[ms][ns] = (f32x4){0.f, 0.f, 0.f, 0.f};
    #pragma unroll
    for (int kk = 0; kk < 4; ++kk) {
      short8 af[4];
      #pragma unroll
      for (int ms = 0; ms < 4; ++ms)
        af[ms] = *(const short8*)&As[((ms * 16 + l15) * 17 + kk * 4 + q) * 8];
      #pragma unroll
      for (int ms = 0; ms < 4; ++ms)
        #pragma unroll
        for (int ns = 0; ns < 2; ++ns)
          acc[ms][ns] = __builtin_amdgcn_mfma_f32_16x16x32_bf16(af[ms], bfr[ns][kk], acc[ms][ns], 0, 0, 0);
    }

    if (msgmode) {
      __syncthreads();
      #pragma unroll
      for (int ms = 0; ms < 4; ++ms)
        #pragma unroll
        for (int ns = 0; ns < 2; ++ns)
          #pragma unroll
          for (int reg = 0; reg < 4; ++reg)
            Es[(ms * 16 + q * 4 + reg) * 136 + wave * 32 + ns * 16 + l15] =
                (short)f2bf(acc[ms][ns][reg]);
      __syncthreads();
      #pragma unroll
      for (int i = 0; i < 4; ++i) {
        int row = wave * 16 + i * 4 + q;
        short8 v = *(const short8*)&Es[row * 136 + l15 * 8];
        if (row < nrows)
          *(short8*)(msg + (size_t)Pos2[0][row] * 128 + l15 * 8) = v;
      }
      __syncthreads();
    } else {
      #pragma unroll
      for (int ms = 0; ms < 4; ++ms)
        #pragma unroll
        for (int reg = 0; reg < 4; ++reg) {
          int mrow = ms * 16 + q * 4 + reg;
          if (mrow < nrows) {
            float* op = out + (size_t)Rows[mrow] * 128 + wave * 32 + l15;
            unsafeAtomicAdd(op, acc[ms][0][reg]);
            unsafeAtomicAdd(op + 16, acc[ms][1][reg]);
          }
        }
      __syncthreads();
    }
  }
}

__global__ __launch_bounds__(256) void k_reduce(const unsigned short* __restrict__ msg,
    const int* __restrict__ dstOff, float* __restrict__ out)
{
  int d = blockIdx.x * 16 + (threadIdx.x >> 4);
  if (d >= NN) return;
  int sl = threadIdx.x & 15;
  int s = dstOff[d], e = dstOff[d + 1];
  const unsigned short* base = msg + (size_t)sl * 8;
  float a[8], bacc[8];
  #pragma unroll
  for (int i = 0; i < 8; ++i) { a[i] = 0.f; bacc[i] = 0.f; }
  int j = s;
  for (; j + 1 < e; j += 2) {
    u32x4 v0 = *(const u32x4*)(base + (size_t)j * 128);
    u32x4 v1 = *(const u32x4*)(base + (size_t)(j + 1) * 128);
    #pragma unroll
    for (int c = 0; c < 4; ++c) {
      a[2 * c]     += __builtin_bit_cast(float, v0[c] << 16);
      a[2 * c + 1] += __builtin_bit_cast(float, v0[c] & 0xffff0000u);
      bacc[2 * c]     += __builtin_bit_cast(float, v1[c] << 16);
      bacc[2 * c + 1] += __builtin_bit_cast(float, v1[c] & 0xffff0000u);
    }
  }
  if (j < e) {
    u32x4 v0 = *(const u32x4*)(base + (size_t)j * 128);
    #pragma unroll
    for (int c = 0; c < 4; ++c) {
      a[2 * c]     += __builtin_bit_cast(float, v0[c] << 16);
      a[2 * c + 1] += __builtin_bit_cast(float, v0[c] & 0xffff0000u);
    }
  }
  float4 w0, w1;
  w0.x = a[0] + bacc[0]; w0.y = a[1] + bacc[1]; w0.z = a[2] + bacc[2]; w0.w = a[3] + bacc[3];
  w1.x = a[4] + bacc[4]; w1.y = a[5] + bacc[5]; w1.z = a[6] + bacc[6]; w1.w = a[7] + bacc[7];
  float* op = out + (size_t)d * 128 + sl * 8;
  *(float4*)op = w0;
  *(float4*)(op + 4) = w1;
}

extern "C" void kernel_launch(void* const* d_in, const int* in_sizes, int n_in,
                              void* d_out, int out_size, void* d_ws, size_t ws_size,
                              hipStream_t stream)
{
  const float* x      = (const float*)d_in[0];
  const int*   ei     = (const int*)d_in[1];
  const int*   et     = (const int*)d_in[2];
  const float* bases  = (const float*)d_in[3];
  const float* coef   = (const float*)d_in[4];
  const float* w_self = (const float*)d_in[5];
  float* out = (float*)d_out;
  char* ws = (char*)d_ws;
  unsigned short* wT = (unsigned short*)(ws + WT_OFF);
  int* meta      = (int*)(ws + META_OFF);
  int* dstHist   = (int*)(ws + DH_OFF);
  int* dstOff    = (int*)(ws + DO_OFF);
  int* dstCursor = (int*)(ws + DC_OFF);
  int* blockSums = (int*)(ws + BS_OFF);
  int2* sCP      = (int2*)(ws + SCP_OFF);
  int* sRow      = (int*)(ws + SR_OFF);
  unsigned short* xb = (unsigned short*)(ws + XB_OFF);

  const int modeB = (ws_size >= NEED_B) ? 1 : 0;
  const int modeA = (modeB || ws_size >= NEED_A) ? 1 : 0;
  unsigned short* msg = (unsigned short*)(ws + (modeB ? MSGB_OFF : MSGA_OFF));

  // deterministic cooperative-grid sizing (same every call -> graph-safe)
  int occ = 0;
  hipOccupancyMaxActiveBlocksPerMultiprocessor(&occ, k_fused, 256, 0);
  int coopGrid = occ * 256;          // 256 CUs on MI355X
  if (coopGrid > 2048) coopGrid = 2048;

  if (modeB && coopGrid >= 256) {
    void* args[] = { (void*)&x, (void*)&ei, (void*)&et, (void*)&bases, (void*)&coef,
                     (void*)&w_self, (void*)&wT, (void*)&meta, (void*)&dstHist,
                     (void*)&dstOff, (void*)&dstCursor, (void*)&blockSums,
                     (void*)&sCP, (void*)&xb, (void*)&msg, (void*)&out };
    hipLaunchCooperativeKernel((void*)k_fused, dim3(coopGrid), dim3(256), args, 0, stream);
    return;
  }

  // -------- fallback: R5 multi-kernel path --------
  hipMemsetAsync(ws + META_OFF, 0, 512 + 400000, stream);
  k_prep<<<modeB ? (WGRID + 12500) : WGRID, 256, 0, stream>>>(bases, coef, w_self, wT, x, xb);
  k_hist<<<256, 256, 0, stream>>>(ei, et, meta, dstHist);
  if (modeA) {
    k_scan1<<<SCANB, 256, 0, stream>>>(dstHist, dstOff, blockSums);
    k_scan2<<<1, 512, 0, stream>>>(blockSums, meta);
    k_scan3<<<SCANB, 256, 0, stream>>>(dstOff, blockSums, dstCursor, sCP);
  } else {
    k_scan2<<<1, 512, 0, stream>>>(blockSums, meta);
    k_self0<<<SCANB, 256, 0, stream>>>(sCP, sRow);
    hipMemsetAsync(d_out, 0, (size_t)NN * D * 4, stream);
  }
  k_scatter<<<(NE + 4095) / 4096, 256, 0, stream>>>(ei, et, meta, sCP, sRow, dstCursor, modeA);
  k_gemm<<<GEMMG, 256, 0, stream>>>(x, xb, wT, meta, sCP, sRow, msg, out, modeB, modeA);
  if (modeA)
    k_reduce<<<(NN + 15) / 16, 256, 0, stream>>>(msg, dstOff, out);
}